// Round 14
// baseline (129.189 us; speedup 1.0000x reference)
//
#include <hip/hip_runtime.h>

// PhysicsGuidedAttention: B=2, N=2048, D=768, H=12, Hd=64
// qkv = x @ w_qkv.T ; flash-attn with elevation bias ; out = attn_out @ w_proj.T + b_proj
// R14: attn = R12 exact (best measured, 57.4 us). gemm1 rebuilt all-bf16 with
//      128x256 tile (A re-reads 18->9, bf16 halves bytes; B L2-resident);
//      x converted up front in cvt3. gemm2 64-row tiles unchanged.

typedef __attribute__((ext_vector_type(8))) short bf16x8;   // 8 bf16 = 4 VGPRs
typedef __attribute__((ext_vector_type(4))) float f32x4;
typedef __attribute__((ext_vector_type(16))) float f32x16;  // 32x32 accumulator

__device__ __forceinline__ unsigned short f2bf(float f) {
  unsigned int u = __builtin_bit_cast(unsigned int, f);
  u += 0x7fffu + ((u >> 16) & 1u);        // round-to-nearest-even
  return (unsigned short)(u >> 16);
}

__device__ __forceinline__ unsigned cvtpk(float lo, float hi) {
  unsigned r;
  asm("v_cvt_pk_bf16_f32 %0, %1, %2" : "=v"(r) : "v"(lo), "v"(hi));
  return r;
}

__device__ __forceinline__ float exp2v(float x) {
  float r;
  asm("v_exp_f32 %0, %1" : "=v"(r) : "v"(x));
  return r;
}

// XOR swizzle on element index: spreads 128B-stride row slots across banks.
__device__ __forceinline__ int sw8(int row) {
  return ((row ^ (row >> 3)) & 7) << 3;
}

__device__ __forceinline__ void gload16(const unsigned short* g, unsigned short* l) {
  __builtin_amdgcn_global_load_lds(
      (const __attribute__((address_space(1))) unsigned int*)g,
      (__attribute__((address_space(3))) unsigned int*)l, 16, 0, 0);
}

// ---------------------------------------------------------------------------
// f32 -> bf16 converts for x, w_qkv, w_proj in ONE launch.
__global__ __launch_bounds__(256)
void cvt3_kernel(const float* __restrict__ a, unsigned short* __restrict__ ao, int na8,
                 const float* __restrict__ b, unsigned short* __restrict__ bo, int nb8,
                 const float* __restrict__ c, unsigned short* __restrict__ co, int nc8) {
  int i = blockIdx.x * 256 + threadIdx.x;
  const float* src; unsigned short* dst;
  if (i < na8) { src = a; dst = ao; }
  else if ((i -= na8) < nb8) { src = b; dst = bo; }
  else if ((i -= nb8) < nc8) { src = c; dst = co; }
  else return;
  const float4 f0 = ((const float4*)src)[i * 2];
  const float4 f1 = ((const float4*)src)[i * 2 + 1];
  uint4 v;
  v.x = cvtpk(f0.x, f0.y);
  v.y = cvtpk(f0.z, f0.w);
  v.z = cvtpk(f1.x, f1.y);
  v.w = cvtpk(f1.z, f1.w);
  ((uint4*)dst)[i] = v;
}

// ---------------------------------------------------------------------------
// gemm1: C[M,N] = A[M,K] @ B[N,K]^T, all-bf16 via gload_lds, C bf16.
// 128x256 tile, BK=32, 2-phase dbuf. 256 thr = 4 waves: wr=w&1 (row 64-group),
// wc=w>>1 (col 128-group); each wave computes 64x128 (4x8 frags).
__global__ __launch_bounds__(256)
void gemm1_kernel(const unsigned short* __restrict__ Ap,
                  const unsigned short* __restrict__ Bp,
                  unsigned short* __restrict__ Cp, int M, int N, int K) {
  __shared__ __align__(16) unsigned short lds_a[2][128 * 32];
  __shared__ __align__(16) unsigned short lds_b[2][256 * 32];
  const int t = threadIdx.x;
  const int l = t & 63;
  const int w = t >> 6;
  const int wr = w & 1, wc = w >> 1;
  const int brow = blockIdx.x * 128;
  const int bcol = blockIdx.y * 256;
  const int l15 = l & 15, l4 = l >> 4;

  const int srow = t >> 2;        // 0..63
  const int scol = (t & 3) * 8;
  const unsigned short* ga = Ap + (size_t)(brow + srow) * K + scol;
  const unsigned short* gb = Bp + (size_t)(bcol + srow) * K + scol;

  f32x4 acc[4][8] = {};
  const int nk = K >> 5;

  {
    unsigned short* la = lds_a[0] + w * 512;
    unsigned short* lb = lds_b[0] + w * 512;
    gload16(ga, la);
    gload16(ga + (size_t)64 * K, la + 2048);
    gload16(gb, lb);
    gload16(gb + (size_t)64 * K, lb + 2048);
    gload16(gb + (size_t)128 * K, lb + 4096);
    gload16(gb + (size_t)192 * K, lb + 6144);
  }
  __syncthreads();

  int buf = 0;
  for (int kt = 0; kt < nk; ++kt) {
    if (kt + 1 < nk) {
      const size_t ko = (size_t)(kt + 1) * 32;
      unsigned short* la = lds_a[buf ^ 1] + w * 512;
      unsigned short* lb = lds_b[buf ^ 1] + w * 512;
      gload16(ga + ko, la);
      gload16(ga + ko + (size_t)64 * K, la + 2048);
      gload16(gb + ko, lb);
      gload16(gb + ko + (size_t)64 * K, lb + 2048);
      gload16(gb + ko + (size_t)128 * K, lb + 4096);
      gload16(gb + ko + (size_t)192 * K, lb + 6144);
    }
    bf16x8 af[4], bfr[8];
#pragma unroll
    for (int i = 0; i < 4; ++i)
      af[i] = *(const bf16x8*)&lds_a[buf][(wr * 64 + i * 16 + l15) * 32 + l4 * 8];
#pragma unroll
    for (int j = 0; j < 8; ++j)
      bfr[j] = *(const bf16x8*)&lds_b[buf][(wc * 128 + j * 16 + l15) * 32 + l4 * 8];
#pragma unroll
    for (int i = 0; i < 4; ++i)
#pragma unroll
      for (int j = 0; j < 8; ++j)
        acc[i][j] = __builtin_amdgcn_mfma_f32_16x16x32_bf16(af[i], bfr[j], acc[i][j], 0, 0, 0);
    __syncthreads();
    buf ^= 1;
  }

#pragma unroll
  for (int i = 0; i < 4; ++i)
#pragma unroll
    for (int j = 0; j < 8; ++j)
#pragma unroll
      for (int r = 0; r < 4; ++r) {
        const int row = brow + wr * 64 + i * 16 + l4 * 4 + r;
        const int col = bcol + wc * 128 + j * 16 + l15;
        Cp[(size_t)row * N + col] = f2bf(acc[i][j][r]);
      }
}

// ---------------------------------------------------------------------------
// gemm2: C[M,N] = A[M,K] @ B[N,K]^T + bias, all-bf16 inputs via gload_lds,
// C f32. 64x128 tile (384 blocks at M=4096,N=768), BK=32, 2-phase dbuf.
__global__ __launch_bounds__(256)
void gemm2_kernel(const unsigned short* __restrict__ Ap,
                  const unsigned short* __restrict__ Bp,
                  const float* __restrict__ bias, float* __restrict__ Cp,
                  int M, int N, int K) {
  __shared__ __align__(16) unsigned short lds_a[2][64 * 32];
  __shared__ __align__(16) unsigned short lds_b[2][128 * 32];
  const int t = threadIdx.x;
  const int l = t & 63;
  const int w = t >> 6;
  const int wr = w >> 1, wc = w & 1;
  const int brow = blockIdx.x * 64;
  const int bcol = blockIdx.y * 128;
  const int l15 = l & 15, l4 = l >> 4;

  const int srow = t >> 2;
  const int scol = (t & 3) * 8;
  const unsigned short* ga = Ap + (size_t)(brow + srow) * K + scol;
  const unsigned short* gb = Bp + (size_t)(bcol + srow) * K + scol;

  f32x4 acc[2][4] = {};
  const int nk = K >> 5;

  {
    gload16(ga, lds_a[0] + w * 512);
    unsigned short* lb = lds_b[0] + w * 512;
    gload16(gb, lb);
    gload16(gb + (size_t)64 * K, lb + 2048);
  }
  __syncthreads();

  int buf = 0;
  for (int kt = 0; kt < nk; ++kt) {
    if (kt + 1 < nk) {
      const size_t ko = (size_t)(kt + 1) * 32;
      gload16(ga + ko, lds_a[buf ^ 1] + w * 512);
      unsigned short* lb = lds_b[buf ^ 1] + w * 512;
      gload16(gb + ko, lb);
      gload16(gb + ko + (size_t)64 * K, lb + 2048);
    }
    bf16x8 af[2], bfr[4];
#pragma unroll
    for (int i = 0; i < 2; ++i)
      af[i] = *(const bf16x8*)&lds_a[buf][(wr * 32 + i * 16 + l15) * 32 + l4 * 8];
#pragma unroll
    for (int j = 0; j < 4; ++j)
      bfr[j] = *(const bf16x8*)&lds_b[buf][(wc * 64 + j * 16 + l15) * 32 + l4 * 8];
#pragma unroll
    for (int i = 0; i < 2; ++i)
#pragma unroll
      for (int j = 0; j < 4; ++j)
        acc[i][j] = __builtin_amdgcn_mfma_f32_16x16x32_bf16(af[i], bfr[j], acc[i][j], 0, 0, 0);
    __syncthreads();
    buf ^= 1;
  }

#pragma unroll
  for (int i = 0; i < 2; ++i)
#pragma unroll
    for (int j = 0; j < 4; ++j)
#pragma unroll
      for (int r = 0; r < 4; ++r) {
        const int row = brow + wr * 32 + i * 16 + l4 * 4 + r;
        const int col = bcol + wc * 64 + j * 16 + l15;
        Cp[(size_t)row * N + col] = acc[i][j][r] + bias[col];
      }
}

// ---------------------------------------------------------------------------
// Flash attention (R12 exact): 32x32x16 MFMA, swapped QK^T, no max-tracking,
// ones-MFMA psum, x2-unrolled main loop with literal buffer indices.
// grid = (B*H, N/256); 512 thr = 8 waves; wave w owns q [q0+32w, q0+32w+32).
__global__ __launch_bounds__(512)
void attn_kernel(const unsigned short* __restrict__ qkv,
                 const float* __restrict__ elev,
                 const float* __restrict__ alpha_p,
                 unsigned short* __restrict__ aout) {
  __shared__ __align__(16) unsigned short lds_k[2][64 * 64];
  __shared__ __align__(16) unsigned short lds_vt[2][64 * 64];   // [d][kv], swizzled
  __shared__ __align__(16) float lds_ej[2][64];

  const int t = threadIdx.x;
  const int l = t & 63;
  const int w = t >> 6;                    // 0..7
  const int l31 = l & 31;
  const int h = l >> 5;
  const int b = blockIdx.x / 12, hd = blockIdx.x % 12;
  const int q0 = blockIdx.y * 256 + w * 32;

  const float cE = fmaxf(alpha_p[0], 0.f) * (1.4426950408889634f * 1e-3f);
  const float c1 = 0.18033688011112042f;   // 0.125 * log2(e)

  const size_t rs = 2304;
  const unsigned short* qbase = qkv + ((size_t)b * 2048) * rs + hd * 64;
  const unsigned short* kbase = qbase + 768;
  const unsigned short* vbase = qbase + 1536;

  bf16x8 qa[4];
  {
    const unsigned short* qp = qbase + (size_t)(q0 + l31) * rs + h * 8;
#pragma unroll
    for (int ks = 0; ks < 4; ++ks) qa[ks] = *(const bf16x8*)(qp + ks * 16);
  }
  const float eiv = elev[(size_t)b * 2048 + q0 + l31] * cE;

  uint4 onesu; onesu.x = onesu.y = onesu.z = onesu.w = 0x3F803F80u;
  const bf16x8 onesf = __builtin_bit_cast(bf16x8, onesu);

  f32x16 o[2] = {};
  f32x16 ps = {};

  const int sr = t >> 3;          // row 0..63
  const int sc = (t & 7) * 8;     // col

  uint4 rk, rv;
  float evn = 0.f;

  // prologue: stage tile 0 into buf 0
  rk = *(const uint4*)(kbase + (size_t)sr * rs + sc);
  rv = *(const uint4*)(vbase + (size_t)sr * rs + sc);
  if (t < 64) evn = elev[(size_t)b * 2048 + t];
  *(uint4*)&lds_k[0][sr * 64 + (sc ^ sw8(sr))] = rk;
  {
    union { uint4 u; unsigned short s[8]; } vu; vu.u = rv;
#pragma unroll
    for (int j = 0; j < 8; ++j) {
      const int d = sc + j;
      lds_vt[0][d * 64 + (sr ^ sw8(d))] = vu.s[j];
    }
  }
  if (t < 64) lds_ej[0][t] = evn * cE;
  __syncthreads();

#define ATTN_STEP(IT, CUR, PRE)                                                \
  {                                                                            \
    if (PRE) {                                                                 \
      const int kv1 = ((IT) + 1) * 64;                                         \
      rk = *(const uint4*)(kbase + (size_t)(kv1 + sr) * rs + sc);              \
      rv = *(const uint4*)(vbase + (size_t)(kv1 + sr) * rs + sc);              \
      if (t < 64) evn = elev[(size_t)b * 2048 + kv1 + t];                      \
    }                                                                          \
    f32x16 st[2] = {};                                                         \
    __builtin_amdgcn_s_setprio(1);                                             \
    _Pragma("unroll")                                                          \
    for (int kst = 0; kst < 4; ++kst) {                                        \
      const int col = kst * 16 + h * 8;                                        \
      _Pragma("unroll")                                                        \
      for (int mb = 0; mb < 2; ++mb) {                                         \
        const int row = mb * 32 + l31;                                         \
        bf16x8 kf = *(const bf16x8*)&lds_k[CUR][row * 64 + (col ^ sw8(row))];  \
        st[mb] = __builtin_amdgcn_mfma_f32_32x32x16_bf16(kf, qa[kst], st[mb], 0, 0, 0); \
      }                                                                        \
    }                                                                          \
    __builtin_amdgcn_s_setprio(0);                                             \
    bf16x8 pa[4];                                                              \
    _Pragma("unroll")                                                          \
    for (int mb = 0; mb < 2; ++mb) {                                           \
      float p16[16];                                                           \
      _Pragma("unroll")                                                        \
      for (int rr = 0; rr < 4; ++rr) {                                         \
        const float4 ejq = *(const float4*)&lds_ej[CUR][mb * 32 + rr * 8 + h * 4]; \
        _Pragma("unroll")                                                      \
        for (int jl = 0; jl < 4; ++jl) {                                       \
          const int r = rr * 4 + jl;                                           \
          const float bm = __builtin_amdgcn_fmed3f(ejq[jl] - eiv, 0.f, 14.4269504f); \
          p16[r] = exp2v(__builtin_fmaf(st[mb][r], c1, -bm));                  \
        }                                                                      \
      }                                                                        \
      _Pragma("unroll")                                                        \
      for (int ks2 = 0; ks2 < 2; ++ks2) {                                      \
        unsigned u0 = cvtpk(p16[ks2 * 8 + 0], p16[ks2 * 8 + 1]);               \
        unsigned u1 = cvtpk(p16[ks2 * 8 + 2], p16[ks2 * 8 + 3]);               \
        unsigned v0 = cvtpk(p16[ks2 * 8 + 4], p16[ks2 * 8 + 5]);               \
        unsigned v1 = cvtpk(p16[ks2 * 8 + 6], p16[ks2 * 8 + 7]);               \
        asm volatile("v_permlane32_swap_b32 %0, %1" : "+v"(u0), "+v"(v0));     \
        asm volatile("v_permlane32_swap_b32 %0, %1" : "+v"(u1), "+v"(v1));     \
        uint4 fr; fr.x = u0; fr.y = u1; fr.z = v0; fr.w = v1;                  \
        pa[mb * 2 + ks2] = __builtin_bit_cast(bf16x8, fr);                     \
      }                                                                        \
    }                                                                          \
    __builtin_amdgcn_s_setprio(1);                                             \
    _Pragma("unroll")                                                          \
    for (int ks = 0; ks < 4; ++ks) {                                           \
      const int col = ks * 16 + h * 8;                                         \
      _Pragma("unroll")                                                        \
      for (int nb = 0; nb < 2; ++nb) {                                         \
        const int row = nb * 32 + l31;                                         \
        bf16x8 vf = *(const bf16x8*)&lds_vt[CUR][row * 64 + (col ^ sw8(row))]; \
        o[nb] = __builtin_amdgcn_mfma_f32_32x32x16_bf16(pa[ks], vf, o[nb], 0, 0, 0); \
      }                                                                        \
      ps = __builtin_amdgcn_mfma_f32_32x32x16_bf16(pa[ks], onesf, ps, 0, 0, 0); \
    }                                                                          \
    __builtin_amdgcn_s_setprio(0);                                             \
    if (PRE) {                                                                 \
      *(uint4*)&lds_k[1 - (CUR)][sr * 64 + (sc ^ sw8(sr))] = rk;               \
      union { uint4 u; unsigned short s[8]; } vu; vu.u = rv;                   \
      _Pragma("unroll")                                                        \
      for (int j = 0; j < 8; ++j) {                                            \
        const int d = sc + j;                                                  \
        lds_vt[1 - (CUR)][d * 64 + (sr ^ sw8(d))] = vu.s[j];                   \
      }                                                                        \
      if (t < 64) lds_ej[1 - (CUR)][t] = evn * cE;                             \
    }                                                                          \
    __syncthreads();                                                           \
  }

  for (int s = 0; s < 16; ++s) {
    ATTN_STEP(2 * s, 0, true);
    ATTN_STEP(2 * s + 1, 1, s < 15);
  }
#undef ATTN_STEP

  // --- epilogue: purely per-lane normalize (ps rows == o rows), store bf16 ---
  float inv[16];
#pragma unroll
  for (int r = 0; r < 16; ++r) inv[r] = 1.0f / ps[r];
#pragma unroll
  for (int nb = 0; nb < 2; ++nb) {
    const int col = hd * 64 + nb * 32 + l31;
#pragma unroll
    for (int rr = 0; rr < 4; ++rr)
#pragma unroll
      for (int jl = 0; jl < 4; ++jl) {
        const int r = rr * 4 + jl;
        const int q = q0 + rr * 8 + h * 4 + jl;
        aout[((size_t)b * 2048 + q) * 768 + col] = f2bf(o[nb][r] * inv[r]);
      }
  }
}

extern "C" void kernel_launch(void* const* d_in, const int* in_sizes, int n_in,
                              void* d_out, int out_size, void* d_ws, size_t ws_size,
                              hipStream_t stream) {
  const float* x      = (const float*)d_in[0];   // [2,2048,768]
  const float* elev   = (const float*)d_in[1];   // [2,2048]
  const float* w_qkv  = (const float*)d_in[2];   // [2304,768]
  const float* w_proj = (const float*)d_in[3];   // [768,768]
  const float* b_proj = (const float*)d_in[4];   // [768]
  const float* alpha  = (const float*)d_in[5];   // [1]
  float* out = (float*)d_out;                    // [2,2048,768] f32

  // ws layout (bf16): qkvb [4096,2304] ; xb(=aob) [4096,768] ; wqkvb [2304,768];
  // wprojb [768,768]  => 29.9 MB total
  unsigned short* qkvb   = (unsigned short*)d_ws;
  unsigned short* xb     = qkvb + (size_t)4096 * 2304;
  unsigned short* aob    = xb;                          // reuse after gemm1
  unsigned short* wqkvb  = xb + (size_t)4096 * 768;
  unsigned short* wprojb = wqkvb + (size_t)2304 * 768;

  cvt3_kernel<<<2688, 256, 0, stream>>>(x, xb, 4096 * 768 / 8,
                                        w_qkv, wqkvb, 2304 * 768 / 8,
                                        w_proj, wprojb, 768 * 768 / 8);

  // 1) qkv = x @ w_qkv^T   (all-bf16, 128x256 tile)
  gemm1_kernel<<<dim3(32, 9), 256, 0, stream>>>(
      xb, wqkvb, qkvb, 4096, 2304, 768);

  // 2) flash attention with elevation bias -> normalized bf16 aob
  attn_kernel<<<dim3(24, 8), 512, 0, stream>>>(qkvb, elev, alpha, aob);

  // 3) out = aob @ w_proj^T + b_proj
  gemm2_kernel<<<dim3(64, 6), 256, 0, stream>>>(
      aob, wprojb, b_proj, out, 4096, 768, 768);
}

// Round 15
// 119.879 us; speedup vs baseline: 1.0777x; 1.0777x over previous
//
#include <hip/hip_runtime.h>

// PhysicsGuidedAttention: B=2, N=2048, D=768, H=12, Hd=64
// qkv = x @ w_qkv.T ; flash-attn with elevation bias ; out = attn_out @ w_proj.T + b_proj
// R15: attn = R12 body + KV-parity split inside 8-wave blocks (4 q-waves x 2
//      parities, per-parity dbuf 64x64 LDS, pure-sum combine in LDS at end).
//      Grid (24,16)=384 blocks -> no idle CUs, up to 4 waves/SIMD.
//      gemm1/gemm2/cvt2 = R12 exact (best measured).

typedef __attribute__((ext_vector_type(8))) short bf16x8;   // 8 bf16 = 4 VGPRs
typedef __attribute__((ext_vector_type(4))) float f32x4;
typedef __attribute__((ext_vector_type(16))) float f32x16;  // 32x32 accumulator

__device__ __forceinline__ unsigned short f2bf(float f) {
  unsigned int u = __builtin_bit_cast(unsigned int, f);
  u += 0x7fffu + ((u >> 16) & 1u);        // round-to-nearest-even
  return (unsigned short)(u >> 16);
}

__device__ __forceinline__ unsigned cvtpk(float lo, float hi) {
  unsigned r;
  asm("v_cvt_pk_bf16_f32 %0, %1, %2" : "=v"(r) : "v"(lo), "v"(hi));
  return r;
}

__device__ __forceinline__ float exp2v(float x) {
  float r;
  asm("v_exp_f32 %0, %1" : "=v"(r) : "v"(x));
  return r;
}

// XOR swizzle on element index: spreads 128B-stride row slots across banks.
__device__ __forceinline__ int sw8(int row) {
  return ((row ^ (row >> 3)) & 7) << 3;
}

__device__ __forceinline__ void gload16(const unsigned short* g, unsigned short* l) {
  __builtin_amdgcn_global_load_lds(
      (const __attribute__((address_space(1))) unsigned int*)g,
      (__attribute__((address_space(3))) unsigned int*)l, 16, 0, 0);
}

// ---------------------------------------------------------------------------
// f32 -> bf16 converts for w_qkv and w_proj in one launch.
__global__ __launch_bounds__(256)
void cvt2_kernel(const float* __restrict__ a, unsigned short* __restrict__ ao, int na8,
                 const float* __restrict__ b, unsigned short* __restrict__ bo, int nb8) {
  int i = blockIdx.x * 256 + threadIdx.x;
  const float* src; unsigned short* dst;
  if (i < na8) { src = a; dst = ao; }
  else {
    i -= na8;
    if (i >= nb8) return;
    src = b; dst = bo;
  }
  const float4 f0 = ((const float4*)src)[i * 2];
  const float4 f1 = ((const float4*)src)[i * 2 + 1];
  uint4 v;
  v.x = cvtpk(f0.x, f0.y);
  v.y = cvtpk(f0.z, f0.w);
  v.z = cvtpk(f1.x, f1.y);
  v.w = cvtpk(f1.z, f1.w);
  ((uint4*)dst)[i] = v;
}

// ---------------------------------------------------------------------------
// gemm1: C[M,N] = A[M,K] @ B[N,K]^T with A = f32 (converted in staging regs),
// B bf16 via gload_lds, C bf16. 128x128 tile, BK=32, 2-phase dbuf (T14 for A).
__global__ __launch_bounds__(256)
void gemm_a32_kernel(const float* __restrict__ Ap,
                     const unsigned short* __restrict__ Bp,
                     unsigned short* __restrict__ Cp, int M, int N, int K) {
  __shared__ __align__(16) unsigned short lds_a[2][128 * 32];
  __shared__ __align__(16) unsigned short lds_b[2][128 * 32];
  const int t = threadIdx.x;
  const int l = t & 63;
  const int w = t >> 6;
  const int wr = w >> 1, wc = w & 1;
  const int bid = blockIdx.x + gridDim.x * blockIdx.y;
  const int xcd = bid & 7;
  const int idx = bid >> 3;
  const int brow = (xcd * 4 + (idx & 3)) * 128;
  const int bcol = (idx >> 2) * 128;
  const int l15 = l & 15, l4 = l >> 4;

  const int srow = t >> 2;
  const int scol = (t & 3) * 8;
  const float* ga = Ap + (size_t)(brow + srow) * K + scol;
  const unsigned short* gb = Bp + (size_t)(bcol + srow) * K + scol;

  f32x4 acc[4][4] = {};
  const int nk = K >> 5;

  float4 fa[4];
  {
    fa[0] = *(const float4*)ga;
    fa[1] = *(const float4*)(ga + 4);
    fa[2] = *(const float4*)(ga + (size_t)64 * K);
    fa[3] = *(const float4*)(ga + (size_t)64 * K + 4);
    unsigned short* lb = lds_b[0] + w * 512;
    gload16(gb, lb);
    gload16(gb + (size_t)64 * K, lb + 2048);
    uint4 u0, u1;
    u0.x = cvtpk(fa[0].x, fa[0].y); u0.y = cvtpk(fa[0].z, fa[0].w);
    u0.z = cvtpk(fa[1].x, fa[1].y); u0.w = cvtpk(fa[1].z, fa[1].w);
    u1.x = cvtpk(fa[2].x, fa[2].y); u1.y = cvtpk(fa[2].z, fa[2].w);
    u1.z = cvtpk(fa[3].x, fa[3].y); u1.w = cvtpk(fa[3].z, fa[3].w);
    *(uint4*)&lds_a[0][srow * 32 + scol] = u0;
    *(uint4*)&lds_a[0][(srow + 64) * 32 + scol] = u1;
  }
  __syncthreads();

  int buf = 0;
  for (int kt = 0; kt < nk; ++kt) {
    const bool more = kt + 1 < nk;
    if (more) {
      const size_t ko = (size_t)(kt + 1) * 32;
      fa[0] = *(const float4*)(ga + ko);
      fa[1] = *(const float4*)(ga + ko + 4);
      fa[2] = *(const float4*)(ga + ko + (size_t)64 * K);
      fa[3] = *(const float4*)(ga + ko + (size_t)64 * K + 4);
      unsigned short* lb = lds_b[buf ^ 1] + w * 512;
      gload16(gb + ko, lb);
      gload16(gb + ko + (size_t)64 * K, lb + 2048);
    }
    bf16x8 af[4], bfr[4];
#pragma unroll
    for (int i = 0; i < 4; ++i) {
      af[i]  = *(const bf16x8*)&lds_a[buf][(wr * 64 + i * 16 + l15) * 32 + l4 * 8];
      bfr[i] = *(const bf16x8*)&lds_b[buf][(wc * 64 + i * 16 + l15) * 32 + l4 * 8];
    }
#pragma unroll
    for (int i = 0; i < 4; ++i)
#pragma unroll
      for (int j = 0; j < 4; ++j)
        acc[i][j] = __builtin_amdgcn_mfma_f32_16x16x32_bf16(af[i], bfr[j], acc[i][j], 0, 0, 0);
    if (more) {
      uint4 u0, u1;
      u0.x = cvtpk(fa[0].x, fa[0].y); u0.y = cvtpk(fa[0].z, fa[0].w);
      u0.z = cvtpk(fa[1].x, fa[1].y); u0.w = cvtpk(fa[1].z, fa[1].w);
      u1.x = cvtpk(fa[2].x, fa[2].y); u1.y = cvtpk(fa[2].z, fa[2].w);
      u1.z = cvtpk(fa[3].x, fa[3].y); u1.w = cvtpk(fa[3].z, fa[3].w);
      *(uint4*)&lds_a[buf ^ 1][srow * 32 + scol] = u0;
      *(uint4*)&lds_a[buf ^ 1][(srow + 64) * 32 + scol] = u1;
    }
    __syncthreads();
    buf ^= 1;
  }

#pragma unroll
  for (int i = 0; i < 4; ++i)
#pragma unroll
    for (int j = 0; j < 4; ++j)
#pragma unroll
      for (int r = 0; r < 4; ++r) {
        const int row = brow + wr * 64 + i * 16 + l4 * 4 + r;
        const int col = bcol + wc * 64 + j * 16 + l15;
        Cp[(size_t)row * N + col] = f2bf(acc[i][j][r]);
      }
}

// ---------------------------------------------------------------------------
// gemm2: C[M,N] = A[M,K] @ B[N,K]^T + bias, all-bf16 inputs via gload_lds,
// C f32. 64x128 tile (384 blocks at M=4096,N=768), BK=32, 2-phase dbuf.
__global__ __launch_bounds__(256)
void gemm2_kernel(const unsigned short* __restrict__ Ap,
                  const unsigned short* __restrict__ Bp,
                  const float* __restrict__ bias, float* __restrict__ Cp,
                  int M, int N, int K) {
  __shared__ __align__(16) unsigned short lds_a[2][64 * 32];
  __shared__ __align__(16) unsigned short lds_b[2][128 * 32];
  const int t = threadIdx.x;
  const int l = t & 63;
  const int w = t >> 6;
  const int wr = w >> 1, wc = w & 1;
  const int brow = blockIdx.x * 64;
  const int bcol = blockIdx.y * 128;
  const int l15 = l & 15, l4 = l >> 4;

  const int srow = t >> 2;
  const int scol = (t & 3) * 8;
  const unsigned short* ga = Ap + (size_t)(brow + srow) * K + scol;
  const unsigned short* gb = Bp + (size_t)(bcol + srow) * K + scol;

  f32x4 acc[2][4] = {};
  const int nk = K >> 5;

  {
    gload16(ga, lds_a[0] + w * 512);
    unsigned short* lb = lds_b[0] + w * 512;
    gload16(gb, lb);
    gload16(gb + (size_t)64 * K, lb + 2048);
  }
  __syncthreads();

  int buf = 0;
  for (int kt = 0; kt < nk; ++kt) {
    if (kt + 1 < nk) {
      const size_t ko = (size_t)(kt + 1) * 32;
      gload16(ga + ko, lds_a[buf ^ 1] + w * 512);
      unsigned short* lb = lds_b[buf ^ 1] + w * 512;
      gload16(gb + ko, lb);
      gload16(gb + ko + (size_t)64 * K, lb + 2048);
    }
    bf16x8 af[2], bfr[4];
#pragma unroll
    for (int i = 0; i < 2; ++i)
      af[i] = *(const bf16x8*)&lds_a[buf][(wr * 32 + i * 16 + l15) * 32 + l4 * 8];
#pragma unroll
    for (int j = 0; j < 4; ++j)
      bfr[j] = *(const bf16x8*)&lds_b[buf][(wc * 64 + j * 16 + l15) * 32 + l4 * 8];
#pragma unroll
    for (int i = 0; i < 2; ++i)
#pragma unroll
      for (int j = 0; j < 4; ++j)
        acc[i][j] = __builtin_amdgcn_mfma_f32_16x16x32_bf16(af[i], bfr[j], acc[i][j], 0, 0, 0);
    __syncthreads();
    buf ^= 1;
  }

#pragma unroll
  for (int i = 0; i < 2; ++i)
#pragma unroll
    for (int j = 0; j < 4; ++j)
#pragma unroll
      for (int r = 0; r < 4; ++r) {
        const int row = brow + wr * 32 + i * 16 + l4 * 4 + r;
        const int col = bcol + wc * 64 + j * 16 + l15;
        Cp[(size_t)row * N + col] = acc[i][j][r] + bias[col];
      }
}

// ---------------------------------------------------------------------------
// Flash attention, 32x32x16 MFMA, swapped QK^T, no max-tracking, ones-MFMA psum.
// KV-parity split: grid=(B*H, N/128), 512 thr = 8 waves = 4 q-waves x 2 parities.
// Wave (wq,par) computes q rows [q0+32wq, +32) over kv tiles 2s+par (s=0..15).
// Per-parity double-buffered 64x64 LDS (R12-proven addressing). Partials are
// pure sums -> intra-block LDS combine at the end.
__global__ __launch_bounds__(512)
void attn_kernel(const unsigned short* __restrict__ qkv,
                 const float* __restrict__ elev,
                 const float* __restrict__ alpha_p,
                 unsigned short* __restrict__ aout) {
  __shared__ __align__(16) unsigned short lds_k[2][2][64 * 64];   // [par][buf]
  __shared__ __align__(16) unsigned short lds_vt[2][2][64 * 64];  // [par][buf][d][kv]
  __shared__ __align__(16) float lds_ej[2][2][64];                // [par][buf]

  const int t = threadIdx.x;
  const int l = t & 63;
  const int w = t >> 6;                    // 0..7
  const int wq = w & 3;
  const int par = w >> 2;
  const int l31 = l & 31;
  const int h = l >> 5;
  const int b = blockIdx.x / 12, hd = blockIdx.x % 12;
  const int q0 = blockIdx.y * 128 + wq * 32;

  const float cE = fmaxf(alpha_p[0], 0.f) * (1.4426950408889634f * 1e-3f);
  const float c1 = 0.18033688011112042f;   // 0.125 * log2(e)

  const size_t rs = 2304;
  const unsigned short* qbase = qkv + ((size_t)b * 2048) * rs + hd * 64;
  const unsigned short* kbase = qbase + 768;
  const unsigned short* vbase = qbase + 1536;

  bf16x8 qa[4];
  {
    const unsigned short* qp = qbase + (size_t)(q0 + l31) * rs + h * 8;
#pragma unroll
    for (int ks = 0; ks < 4; ++ks) qa[ks] = *(const bf16x8*)(qp + ks * 16);
  }
  const float eiv = elev[(size_t)b * 2048 + q0 + l31] * cE;

  uint4 onesu; onesu.x = onesu.y = onesu.z = onesu.w = 0x3F803F80u;
  const bf16x8 onesf = __builtin_bit_cast(bf16x8, onesu);

  f32x16 o[2] = {};
  f32x16 ps = {};

  // staging: 512 threads cover ONE 64x64 tile; each thread stages both tiles.
  const int sr = t >> 3;          // row 0..63
  const int sc = (t & 7) * 8;     // col

  uint4 rk[2], rv[2];
  float evn = 0.f;
  const int ejp = t >> 6;         // ej staging parity for t<128 (0 or 1)

  // ---- prologue: stage tiles 0 (par0) and 1 (par1) into buf 0 ----
#pragma unroll
  for (int p = 0; p < 2; ++p) {
    rk[p] = *(const uint4*)(kbase + (size_t)(p * 64 + sr) * rs + sc);
    rv[p] = *(const uint4*)(vbase + (size_t)(p * 64 + sr) * rs + sc);
  }
  if (t < 128) evn = elev[(size_t)b * 2048 + ejp * 64 + (t & 63)];
#pragma unroll
  for (int p = 0; p < 2; ++p) {
    *(uint4*)&lds_k[p][0][sr * 64 + (sc ^ sw8(sr))] = rk[p];
    union { uint4 u; unsigned short s[8]; } vu; vu.u = rv[p];
#pragma unroll
    for (int j = 0; j < 8; ++j) {
      const int d = sc + j;
      lds_vt[p][0][d * 64 + (sr ^ sw8(d))] = vu.s[j];
    }
  }
  if (t < 128) lds_ej[ejp][0][t & 63] = evn * cE;
  __syncthreads();

  for (int s = 0; s < 16; ++s) {
    const int cur = s & 1;
    const bool more = s < 15;
    if (more) {                            // prefetch tiles 2s+2, 2s+3 into regs
      const int kvn = (2 * (s + 1)) * 64;
#pragma unroll
      for (int p = 0; p < 2; ++p) {
        rk[p] = *(const uint4*)(kbase + (size_t)(kvn + p * 64 + sr) * rs + sc);
        rv[p] = *(const uint4*)(vbase + (size_t)(kvn + p * 64 + sr) * rs + sc);
      }
      if (t < 128) evn = elev[(size_t)b * 2048 + kvn + ejp * 64 + (t & 63)];
    }

    // --- S^T = K x Q  (tile 2s+par, from this parity's buffer) ---
    f32x16 st[2] = {};
    __builtin_amdgcn_s_setprio(1);
#pragma unroll
    for (int kst = 0; kst < 4; ++kst) {
      const int col = kst * 16 + h * 8;
#pragma unroll
      for (int mb = 0; mb < 2; ++mb) {
        const int row = mb * 32 + l31;
        bf16x8 kf = *(const bf16x8*)&lds_k[par][cur][row * 64 + (col ^ sw8(row))];
        st[mb] = __builtin_amdgcn_mfma_f32_32x32x16_bf16(kf, qa[kst], st[mb], 0, 0, 0);
      }
    }
    __builtin_amdgcn_s_setprio(0);

    // --- softmax (no max-tracking) + in-register P pack ---
    bf16x8 pa[4];
#pragma unroll
    for (int mb = 0; mb < 2; ++mb) {
      float p16[16];
#pragma unroll
      for (int rr = 0; rr < 4; ++rr) {
        const float4 ejq = *(const float4*)&lds_ej[par][cur][mb * 32 + rr * 8 + h * 4];
#pragma unroll
        for (int jl = 0; jl < 4; ++jl) {
          const int r = rr * 4 + jl;
          const float bm = __builtin_amdgcn_fmed3f(ejq[jl] - eiv, 0.f, 14.4269504f);
          p16[r] = exp2v(__builtin_fmaf(st[mb][r], c1, -bm));
        }
      }
#pragma unroll
      for (int ks2 = 0; ks2 < 2; ++ks2) {
        unsigned u0 = cvtpk(p16[ks2 * 8 + 0], p16[ks2 * 8 + 1]);
        unsigned u1 = cvtpk(p16[ks2 * 8 + 2], p16[ks2 * 8 + 3]);
        unsigned v0 = cvtpk(p16[ks2 * 8 + 4], p16[ks2 * 8 + 5]);
        unsigned v1 = cvtpk(p16[ks2 * 8 + 6], p16[ks2 * 8 + 7]);
        asm volatile("v_permlane32_swap_b32 %0, %1" : "+v"(u0), "+v"(v0));
        asm volatile("v_permlane32_swap_b32 %0, %1" : "+v"(u1), "+v"(v1));
        uint4 fr; fr.x = u0; fr.y = u1; fr.z = v0; fr.w = v1;
        pa[mb * 2 + ks2] = __builtin_bit_cast(bf16x8, fr);
      }
    }

    // --- O += P @ V ; psum via ones-MFMA ---
    __builtin_amdgcn_s_setprio(1);
#pragma unroll
    for (int ks = 0; ks < 4; ++ks) {
      const int col = ks * 16 + h * 8;
#pragma unroll
      for (int nb = 0; nb < 2; ++nb) {
        const int row = nb * 32 + l31;
        bf16x8 vf = *(const bf16x8*)&lds_vt[par][cur][row * 64 + (col ^ sw8(row))];
        o[nb] = __builtin_amdgcn_mfma_f32_32x32x16_bf16(pa[ks], vf, o[nb], 0, 0, 0);
      }
      ps = __builtin_amdgcn_mfma_f32_32x32x16_bf16(pa[ks], onesf, ps, 0, 0, 0);
    }
    __builtin_amdgcn_s_setprio(0);

    // --- T14 late-write tiles 2s+2, 2s+3 ---
    if (more) {
      const int nxt = cur ^ 1;
#pragma unroll
      for (int p = 0; p < 2; ++p) {
        *(uint4*)&lds_k[p][nxt][sr * 64 + (sc ^ sw8(sr))] = rk[p];
        union { uint4 u; unsigned short s[8]; } vu; vu.u = rv[p];
#pragma unroll
        for (int j = 0; j < 8; ++j) {
          const int d = sc + j;
          lds_vt[p][nxt][d * 64 + (sr ^ sw8(d))] = vu.s[j];
        }
      }
      if (t < 128) lds_ej[ejp][nxt][t & 63] = evn * cE;
    }
    __syncthreads();
  }

  // --- combine parities (pure sums) via LDS, then normalize + store ---
  float* xO = (float*)lds_k;               // 8192 f32 (32 KB)
  float* xP = (float*)lds_vt;              // 8192 f32
  const int cbase = (wq * 64 + l) * 16;
  if (par == 1) {
#pragma unroll
    for (int r = 0; r < 16; ++r) {
      xO[cbase + r] = o[0][r];
      xO[4096 + cbase + r] = o[1][r];
      xP[cbase + r] = ps[r];
    }
  }
  __syncthreads();
  if (par == 0) {
    float inv[16];
#pragma unroll
    for (int r = 0; r < 16; ++r) {
      o[0][r] += xO[cbase + r];
      o[1][r] += xO[4096 + cbase + r];
      inv[r] = 1.0f / (ps[r] + xP[cbase + r]);
    }
#pragma unroll
    for (int nb = 0; nb < 2; ++nb) {
      const int col = hd * 64 + nb * 32 + l31;
#pragma unroll
      for (int rr = 0; rr < 4; ++rr)
#pragma unroll
        for (int jl = 0; jl < 4; ++jl) {
          const int r = rr * 4 + jl;
          const int q = q0 + rr * 8 + h * 4 + jl;
          aout[((size_t)b * 2048 + q) * 768 + col] = f2bf(o[nb][r] * inv[r]);
        }
    }
  }
}

extern "C" void kernel_launch(void* const* d_in, const int* in_sizes, int n_in,
                              void* d_out, int out_size, void* d_ws, size_t ws_size,
                              hipStream_t stream) {
  const float* x      = (const float*)d_in[0];   // [2,2048,768]
  const float* elev   = (const float*)d_in[1];   // [2,2048]
  const float* w_qkv  = (const float*)d_in[2];   // [2304,768]
  const float* w_proj = (const float*)d_in[3];   // [768,768]
  const float* b_proj = (const float*)d_in[4];   // [768]
  const float* alpha  = (const float*)d_in[5];   // [1]
  float* out = (float*)d_out;                    // [2,2048,768] f32

  // ws layout (bf16): qkvb [4096,2304] ; aob [4096,768] ; wqkvb [2304,768] ;
  // wprojb [768,768]  => 29.9 MB total
  unsigned short* qkvb   = (unsigned short*)d_ws;
  unsigned short* aob    = qkvb + (size_t)4096 * 2304;
  unsigned short* wqkvb  = aob + (size_t)4096 * 768;
  unsigned short* wprojb = wqkvb + (size_t)2304 * 768;

  cvt2_kernel<<<1152, 256, 0, stream>>>(w_qkv, wqkvb, 2304 * 768 / 8,
                                        w_proj, wprojb, 768 * 768 / 8);

  gemm_a32_kernel<<<dim3(32, 18), 256, 0, stream>>>(
      x, wqkvb, qkvb, 4096, 2304, 768);

  attn_kernel<<<dim3(24, 16), 512, 0, stream>>>(qkvb, elev, alpha, aob);

  gemm2_kernel<<<dim3(64, 6), 256, 0, stream>>>(
      aob, wprojb, b_proj, out, 4096, 768, 768);
}

// Round 16
// 100.367 us; speedup vs baseline: 1.2872x; 1.1944x over previous
//
#include <hip/hip_runtime.h>

// PhysicsGuidedAttention: B=2, N=2048, D=768, H=12, Hd=64
// qkv = x @ w_qkv.T ; flash-attn with elevation bias ; out = attn_out @ w_proj.T + b_proj
// R16 = R12 exact (best measured: 100.2 us total, attn 57.4):
//   - attn: 8-wave/512-thr blocks, 256 q each, swapped QK^T on 32x32x16 MFMA,
//     no-max log2 softmax, in-register P via cvt_pk+permlane32_swap, ones-MFMA
//     psum with per-lane normalize, dbuf + T14 reg-staging, x2-unrolled loop.
//   - gemm1: f32-A converted in staging regs (T14 late-write), B via gload_lds.
//   - gemm2: 64x128 tiles, all-bf16 gload_lds.
// Rejected by measurement: KV-parity split (R15), 128-kv spans (R13), bf16-A
// gemm1 (R5/R14), XCD remap isolation (R12 neutral, kept), q-doubling (R9),
// gload_lds K in attn (R4), grid-level kv-split (R8).

typedef __attribute__((ext_vector_type(8))) short bf16x8;   // 8 bf16 = 4 VGPRs
typedef __attribute__((ext_vector_type(4))) float f32x4;
typedef __attribute__((ext_vector_type(16))) float f32x16;  // 32x32 accumulator

__device__ __forceinline__ unsigned short f2bf(float f) {
  unsigned int u = __builtin_bit_cast(unsigned int, f);
  u += 0x7fffu + ((u >> 16) & 1u);        // round-to-nearest-even
  return (unsigned short)(u >> 16);
}

__device__ __forceinline__ unsigned cvtpk(float lo, float hi) {
  unsigned r;
  asm("v_cvt_pk_bf16_f32 %0, %1, %2" : "=v"(r) : "v"(lo), "v"(hi));
  return r;
}

__device__ __forceinline__ float exp2v(float x) {
  float r;
  asm("v_exp_f32 %0, %1" : "=v"(r) : "v"(x));
  return r;
}

// XOR swizzle on element index: spreads 128B-stride row slots across banks.
__device__ __forceinline__ int sw8(int row) {
  return ((row ^ (row >> 3)) & 7) << 3;
}

__device__ __forceinline__ void gload16(const unsigned short* g, unsigned short* l) {
  __builtin_amdgcn_global_load_lds(
      (const __attribute__((address_space(1))) unsigned int*)g,
      (__attribute__((address_space(3))) unsigned int*)l, 16, 0, 0);
}

// ---------------------------------------------------------------------------
// f32 -> bf16 converts for w_qkv and w_proj in one launch.
__global__ __launch_bounds__(256)
void cvt2_kernel(const float* __restrict__ a, unsigned short* __restrict__ ao, int na8,
                 const float* __restrict__ b, unsigned short* __restrict__ bo, int nb8) {
  int i = blockIdx.x * 256 + threadIdx.x;
  const float* src; unsigned short* dst;
  if (i < na8) { src = a; dst = ao; }
  else {
    i -= na8;
    if (i >= nb8) return;
    src = b; dst = bo;
  }
  const float4 f0 = ((const float4*)src)[i * 2];
  const float4 f1 = ((const float4*)src)[i * 2 + 1];
  uint4 v;
  v.x = cvtpk(f0.x, f0.y);
  v.y = cvtpk(f0.z, f0.w);
  v.z = cvtpk(f1.x, f1.y);
  v.w = cvtpk(f1.z, f1.w);
  ((uint4*)dst)[i] = v;
}

// ---------------------------------------------------------------------------
// gemm1: C[M,N] = A[M,K] @ B[N,K]^T with A = f32 (converted in staging regs),
// B bf16 via gload_lds, C bf16. 128x128 tile, BK=32, 2-phase dbuf (T14 for A).
__global__ __launch_bounds__(256)
void gemm_a32_kernel(const float* __restrict__ Ap,
                     const unsigned short* __restrict__ Bp,
                     unsigned short* __restrict__ Cp, int M, int N, int K) {
  __shared__ __align__(16) unsigned short lds_a[2][128 * 32];
  __shared__ __align__(16) unsigned short lds_b[2][128 * 32];
  const int t = threadIdx.x;
  const int l = t & 63;
  const int w = t >> 6;
  const int wr = w >> 1, wc = w & 1;
  const int bid = blockIdx.x + gridDim.x * blockIdx.y;   // linear dispatch order
  const int xcd = bid & 7;
  const int idx = bid >> 3;                              // 0..71
  const int brow = (xcd * 4 + (idx & 3)) * 128;
  const int bcol = (idx >> 2) * 128;
  const int l15 = l & 15, l4 = l >> 4;

  const int srow = t >> 2;
  const int scol = (t & 3) * 8;
  const float* ga = Ap + (size_t)(brow + srow) * K + scol;
  const unsigned short* gb = Bp + (size_t)(bcol + srow) * K + scol;

  f32x4 acc[4][4] = {};
  const int nk = K >> 5;

  float4 fa[4];
  // prologue: tile 0
  {
    fa[0] = *(const float4*)ga;
    fa[1] = *(const float4*)(ga + 4);
    fa[2] = *(const float4*)(ga + (size_t)64 * K);
    fa[3] = *(const float4*)(ga + (size_t)64 * K + 4);
    unsigned short* lb = lds_b[0] + w * 512;
    gload16(gb, lb);
    gload16(gb + (size_t)64 * K, lb + 2048);
    uint4 u0, u1;
    u0.x = cvtpk(fa[0].x, fa[0].y); u0.y = cvtpk(fa[0].z, fa[0].w);
    u0.z = cvtpk(fa[1].x, fa[1].y); u0.w = cvtpk(fa[1].z, fa[1].w);
    u1.x = cvtpk(fa[2].x, fa[2].y); u1.y = cvtpk(fa[2].z, fa[2].w);
    u1.z = cvtpk(fa[3].x, fa[3].y); u1.w = cvtpk(fa[3].z, fa[3].w);
    *(uint4*)&lds_a[0][srow * 32 + scol] = u0;
    *(uint4*)&lds_a[0][(srow + 64) * 32 + scol] = u1;
  }
  __syncthreads();

  int buf = 0;
  for (int kt = 0; kt < nk; ++kt) {
    const bool more = kt + 1 < nk;
    if (more) {                            // issue next-tile loads early
      const size_t ko = (size_t)(kt + 1) * 32;
      fa[0] = *(const float4*)(ga + ko);
      fa[1] = *(const float4*)(ga + ko + 4);
      fa[2] = *(const float4*)(ga + ko + (size_t)64 * K);
      fa[3] = *(const float4*)(ga + ko + (size_t)64 * K + 4);
      unsigned short* lb = lds_b[buf ^ 1] + w * 512;
      gload16(gb + ko, lb);
      gload16(gb + ko + (size_t)64 * K, lb + 2048);
    }
    bf16x8 af[4], bfr[4];
#pragma unroll
    for (int i = 0; i < 4; ++i) {
      af[i]  = *(const bf16x8*)&lds_a[buf][(wr * 64 + i * 16 + l15) * 32 + l4 * 8];
      bfr[i] = *(const bf16x8*)&lds_b[buf][(wc * 64 + i * 16 + l15) * 32 + l4 * 8];
    }
#pragma unroll
    for (int i = 0; i < 4; ++i)
#pragma unroll
      for (int j = 0; j < 4; ++j)
        acc[i][j] = __builtin_amdgcn_mfma_f32_16x16x32_bf16(af[i], bfr[j], acc[i][j], 0, 0, 0);
    if (more) {                            // T14 late-write A (hidden under MFMA)
      uint4 u0, u1;
      u0.x = cvtpk(fa[0].x, fa[0].y); u0.y = cvtpk(fa[0].z, fa[0].w);
      u0.z = cvtpk(fa[1].x, fa[1].y); u0.w = cvtpk(fa[1].z, fa[1].w);
      u1.x = cvtpk(fa[2].x, fa[2].y); u1.y = cvtpk(fa[2].z, fa[2].w);
      u1.z = cvtpk(fa[3].x, fa[3].y); u1.w = cvtpk(fa[3].z, fa[3].w);
      *(uint4*)&lds_a[buf ^ 1][srow * 32 + scol] = u0;
      *(uint4*)&lds_a[buf ^ 1][(srow + 64) * 32 + scol] = u1;
    }
    __syncthreads();
    buf ^= 1;
  }

#pragma unroll
  for (int i = 0; i < 4; ++i)
#pragma unroll
    for (int j = 0; j < 4; ++j)
#pragma unroll
      for (int r = 0; r < 4; ++r) {
        const int row = brow + wr * 64 + i * 16 + l4 * 4 + r;
        const int col = bcol + wc * 64 + j * 16 + l15;
        Cp[(size_t)row * N + col] = f2bf(acc[i][j][r]);
      }
}

// ---------------------------------------------------------------------------
// gemm2: C[M,N] = A[M,K] @ B[N,K]^T + bias, all-bf16 inputs via gload_lds,
// C f32. 64x128 tile (384 blocks at M=4096,N=768), BK=32, 2-phase dbuf.
__global__ __launch_bounds__(256)
void gemm2_kernel(const unsigned short* __restrict__ Ap,
                  const unsigned short* __restrict__ Bp,
                  const float* __restrict__ bias, float* __restrict__ Cp,
                  int M, int N, int K) {
  __shared__ __align__(16) unsigned short lds_a[2][64 * 32];
  __shared__ __align__(16) unsigned short lds_b[2][128 * 32];
  const int t = threadIdx.x;
  const int l = t & 63;
  const int w = t >> 6;
  const int wr = w >> 1, wc = w & 1;          // wave: rows wr*32, cols wc*64
  const int brow = blockIdx.x * 64;
  const int bcol = blockIdx.y * 128;
  const int l15 = l & 15, l4 = l >> 4;

  const int srow = t >> 2;
  const int scol = (t & 3) * 8;
  const unsigned short* ga = Ap + (size_t)(brow + srow) * K + scol;
  const unsigned short* gb = Bp + (size_t)(bcol + srow) * K + scol;

  f32x4 acc[2][4] = {};
  const int nk = K >> 5;

  {
    gload16(ga, lds_a[0] + w * 512);
    unsigned short* lb = lds_b[0] + w * 512;
    gload16(gb, lb);
    gload16(gb + (size_t)64 * K, lb + 2048);
  }
  __syncthreads();

  int buf = 0;
  for (int kt = 0; kt < nk; ++kt) {
    if (kt + 1 < nk) {
      const size_t ko = (size_t)(kt + 1) * 32;
      gload16(ga + ko, lds_a[buf ^ 1] + w * 512);
      unsigned short* lb = lds_b[buf ^ 1] + w * 512;
      gload16(gb + ko, lb);
      gload16(gb + ko + (size_t)64 * K, lb + 2048);
    }
    bf16x8 af[2], bfr[4];
#pragma unroll
    for (int i = 0; i < 2; ++i)
      af[i] = *(const bf16x8*)&lds_a[buf][(wr * 32 + i * 16 + l15) * 32 + l4 * 8];
#pragma unroll
    for (int j = 0; j < 4; ++j)
      bfr[j] = *(const bf16x8*)&lds_b[buf][(wc * 64 + j * 16 + l15) * 32 + l4 * 8];
#pragma unroll
    for (int i = 0; i < 2; ++i)
#pragma unroll
      for (int j = 0; j < 4; ++j)
        acc[i][j] = __builtin_amdgcn_mfma_f32_16x16x32_bf16(af[i], bfr[j], acc[i][j], 0, 0, 0);
    __syncthreads();
    buf ^= 1;
  }

#pragma unroll
  for (int i = 0; i < 2; ++i)
#pragma unroll
    for (int j = 0; j < 4; ++j)
#pragma unroll
      for (int r = 0; r < 4; ++r) {
        const int row = brow + wr * 32 + i * 16 + l4 * 4 + r;
        const int col = bcol + wc * 64 + j * 16 + l15;
        Cp[(size_t)row * N + col] = acc[i][j][r] + bias[col];
      }
}

// ---------------------------------------------------------------------------
// Flash attention: 32x32x16 MFMA, swapped QK^T, no max-tracking, ones-MFMA psum,
// x2-unrolled main loop with literal buffer indices.
// grid = (B*H, N/256); 512 thr = 8 waves; wave w owns q [q0+32w, q0+32w+32).
__global__ __launch_bounds__(512)
void attn_kernel(const unsigned short* __restrict__ qkv,
                 const float* __restrict__ elev,
                 const float* __restrict__ alpha_p,
                 unsigned short* __restrict__ aout) {
  __shared__ __align__(16) unsigned short lds_k[2][64 * 64];
  __shared__ __align__(16) unsigned short lds_vt[2][64 * 64];   // [d][kv], swizzled
  __shared__ __align__(16) float lds_ej[2][64];

  const int t = threadIdx.x;
  const int l = t & 63;
  const int w = t >> 6;                    // 0..7
  const int l31 = l & 31;
  const int h = l >> 5;
  const int b = blockIdx.x / 12, hd = blockIdx.x % 12;
  const int q0 = blockIdx.y * 256 + w * 32;

  const float cE = fmaxf(alpha_p[0], 0.f) * (1.4426950408889634f * 1e-3f);
  const float c1 = 0.18033688011112042f;   // 0.125 * log2(e)

  const size_t rs = 2304;
  const unsigned short* qbase = qkv + ((size_t)b * 2048) * rs + hd * 64;
  const unsigned short* kbase = qbase + 768;
  const unsigned short* vbase = qbase + 1536;

  bf16x8 qa[4];
  {
    const unsigned short* qp = qbase + (size_t)(q0 + l31) * rs + h * 8;
#pragma unroll
    for (int ks = 0; ks < 4; ++ks) qa[ks] = *(const bf16x8*)(qp + ks * 16);
  }
  const float eiv = elev[(size_t)b * 2048 + q0 + l31] * cE;

  uint4 onesu; onesu.x = onesu.y = onesu.z = onesu.w = 0x3F803F80u;
  const bf16x8 onesf = __builtin_bit_cast(bf16x8, onesu);

  f32x16 o[2] = {};
  f32x16 ps = {};

  const int sr = t >> 3;          // row 0..63
  const int sc = (t & 7) * 8;     // col

  uint4 rk, rv;
  float evn = 0.f;

  // prologue: stage tile 0 into buf 0
  rk = *(const uint4*)(kbase + (size_t)sr * rs + sc);
  rv = *(const uint4*)(vbase + (size_t)sr * rs + sc);
  if (t < 64) evn = elev[(size_t)b * 2048 + t];
  *(uint4*)&lds_k[0][sr * 64 + (sc ^ sw8(sr))] = rk;
  {
    union { uint4 u; unsigned short s[8]; } vu; vu.u = rv;
#pragma unroll
    for (int j = 0; j < 8; ++j) {
      const int d = sc + j;
      lds_vt[0][d * 64 + (sr ^ sw8(d))] = vu.s[j];
    }
  }
  if (t < 64) lds_ej[0][t] = evn * cE;
  __syncthreads();

#define ATTN_STEP(IT, CUR, PRE)                                                \
  {                                                                            \
    if (PRE) {                                                                 \
      const int kv1 = ((IT) + 1) * 64;                                         \
      rk = *(const uint4*)(kbase + (size_t)(kv1 + sr) * rs + sc);              \
      rv = *(const uint4*)(vbase + (size_t)(kv1 + sr) * rs + sc);              \
      if (t < 64) evn = elev[(size_t)b * 2048 + kv1 + t];                      \
    }                                                                          \
    f32x16 st[2] = {};                                                         \
    __builtin_amdgcn_s_setprio(1);                                             \
    _Pragma("unroll")                                                          \
    for (int kst = 0; kst < 4; ++kst) {                                        \
      const int col = kst * 16 + h * 8;                                        \
      _Pragma("unroll")                                                        \
      for (int mb = 0; mb < 2; ++mb) {                                         \
        const int row = mb * 32 + l31;                                         \
        bf16x8 kf = *(const bf16x8*)&lds_k[CUR][row * 64 + (col ^ sw8(row))];  \
        st[mb] = __builtin_amdgcn_mfma_f32_32x32x16_bf16(kf, qa[kst], st[mb], 0, 0, 0); \
      }                                                                        \
    }                                                                          \
    __builtin_amdgcn_s_setprio(0);                                             \
    bf16x8 pa[4];                                                              \
    _Pragma("unroll")                                                          \
    for (int mb = 0; mb < 2; ++mb) {                                           \
      float p16[16];                                                           \
      _Pragma("unroll")                                                        \
      for (int rr = 0; rr < 4; ++rr) {                                         \
        const float4 ejq = *(const float4*)&lds_ej[CUR][mb * 32 + rr * 8 + h * 4]; \
        _Pragma("unroll")                                                      \
        for (int jl = 0; jl < 4; ++jl) {                                       \
          const int r = rr * 4 + jl;                                           \
          const float bm = __builtin_amdgcn_fmed3f(ejq[jl] - eiv, 0.f, 14.4269504f); \
          p16[r] = exp2v(__builtin_fmaf(st[mb][r], c1, -bm));                  \
        }                                                                      \
      }                                                                        \
      _Pragma("unroll")                                                        \
      for (int ks2 = 0; ks2 < 2; ++ks2) {                                      \
        unsigned u0 = cvtpk(p16[ks2 * 8 + 0], p16[ks2 * 8 + 1]);               \
        unsigned u1 = cvtpk(p16[ks2 * 8 + 2], p16[ks2 * 8 + 3]);               \
        unsigned v0 = cvtpk(p16[ks2 * 8 + 4], p16[ks2 * 8 + 5]);               \
        unsigned v1 = cvtpk(p16[ks2 * 8 + 6], p16[ks2 * 8 + 7]);               \
        asm volatile("v_permlane32_swap_b32 %0, %1" : "+v"(u0), "+v"(v0));     \
        asm volatile("v_permlane32_swap_b32 %0, %1" : "+v"(u1), "+v"(v1));     \
        uint4 fr; fr.x = u0; fr.y = u1; fr.z = v0; fr.w = v1;                  \
        pa[mb * 2 + ks2] = __builtin_bit_cast(bf16x8, fr);                     \
      }                                                                        \
    }                                                                          \
    __builtin_amdgcn_s_setprio(1);                                             \
    _Pragma("unroll")                                                          \
    for (int ks = 0; ks < 4; ++ks) {                                           \
      const int col = ks * 16 + h * 8;                                         \
      _Pragma("unroll")                                                        \
      for (int nb = 0; nb < 2; ++nb) {                                         \
        const int row = nb * 32 + l31;                                         \
        bf16x8 vf = *(const bf16x8*)&lds_vt[CUR][row * 64 + (col ^ sw8(row))]; \
        o[nb] = __builtin_amdgcn_mfma_f32_32x32x16_bf16(pa[ks], vf, o[nb], 0, 0, 0); \
      }                                                                        \
      ps = __builtin_amdgcn_mfma_f32_32x32x16_bf16(pa[ks], onesf, ps, 0, 0, 0); \
    }                                                                          \
    __builtin_amdgcn_s_setprio(0);                                             \
    if (PRE) {                                                                 \
      *(uint4*)&lds_k[1 - (CUR)][sr * 64 + (sc ^ sw8(sr))] = rk;               \
      union { uint4 u; unsigned short s[8]; } vu; vu.u = rv;                   \
      _Pragma("unroll")                                                        \
      for (int j = 0; j < 8; ++j) {                                            \
        const int d = sc + j;                                                  \
        lds_vt[1 - (CUR)][d * 64 + (sr ^ sw8(d))] = vu.s[j];                   \
      }                                                                        \
      if (t < 64) lds_ej[1 - (CUR)][t] = evn * cE;                             \
    }                                                                          \
    __syncthreads();                                                           \
  }

  for (int s = 0; s < 16; ++s) {
    ATTN_STEP(2 * s, 0, true);
    ATTN_STEP(2 * s + 1, 1, s < 15);
  }
#undef ATTN_STEP

  // --- epilogue: purely per-lane normalize (ps rows == o rows), store bf16 ---
  float inv[16];
#pragma unroll
  for (int r = 0; r < 16; ++r) inv[r] = 1.0f / ps[r];
#pragma unroll
  for (int nb = 0; nb < 2; ++nb) {
    const int col = hd * 64 + nb * 32 + l31;
#pragma unroll
    for (int rr = 0; rr < 4; ++rr)
#pragma unroll
      for (int jl = 0; jl < 4; ++jl) {
        const int r = rr * 4 + jl;
        const int q = q0 + rr * 8 + h * 4 + jl;
        aout[((size_t)b * 2048 + q) * 768 + col] = f2bf(o[nb][r] * inv[r]);
      }
  }
}

extern "C" void kernel_launch(void* const* d_in, const int* in_sizes, int n_in,
                              void* d_out, int out_size, void* d_ws, size_t ws_size,
                              hipStream_t stream) {
  const float* x      = (const float*)d_in[0];   // [2,2048,768]
  const float* elev   = (const float*)d_in[1];   // [2,2048]
  const float* w_qkv  = (const float*)d_in[2];   // [2304,768]
  const float* w_proj = (const float*)d_in[3];   // [768,768]
  const float* b_proj = (const float*)d_in[4];   // [768]
  const float* alpha  = (const float*)d_in[5];   // [1]
  float* out = (float*)d_out;                    // [2,2048,768] f32

  // ws layout (bf16): qkvb [4096,2304] ; aob [4096,768] ; wqkvb [2304,768] ;
  // wprojb [768,768]  => 29.9 MB total
  unsigned short* qkvb   = (unsigned short*)d_ws;
  unsigned short* aob    = qkvb + (size_t)4096 * 2304;
  unsigned short* wqkvb  = aob + (size_t)4096 * 768;
  unsigned short* wprojb = wqkvb + (size_t)2304 * 768;

  // convert the two weight matrices (x is converted inside gemm1 staging)
  cvt2_kernel<<<1152, 256, 0, stream>>>(w_qkv, wqkvb, 2304 * 768 / 8,
                                        w_proj, wprojb, 768 * 768 / 8);

  // 1) qkv = x @ w_qkv^T   (A = f32 x, converted in-register)
  gemm_a32_kernel<<<dim3(32, 18), 256, 0, stream>>>(
      x, wqkvb, qkvb, 4096, 2304, 768);

  // 2) flash attention with elevation bias -> normalized bf16 aob
  attn_kernel<<<dim3(24, 8), 512, 0, stream>>>(qkvb, elev, alpha, aob);

  // 3) out = aob @ w_proj^T + b_proj
  gemm2_kernel<<<dim3(64, 6), 256, 0, stream>>>(
      aob, wprojb, b_proj, out, 4096, 768, 768);
}